// Round 1
// baseline (353.949 us; speedup 1.0000x reference)
//
#include <hip/hip_runtime.h>
#include <cstdint>

// Problem constants
#define BB 8
#define NN 1024
#define CC 256
#define NHEAD 4
#define HDIM 64

// ---------------------------------------------------------------------------
// 1) xm[b,n] = mean over C of x[b,n,:]   (one wave per row)
__global__ void k_xm(const float* __restrict__ x, float* __restrict__ xm) {
  int row = (blockIdx.x << 2) + (threadIdx.x >> 6);   // 4 waves / block
  int lane = threadIdx.x & 63;
  const float* p = x + (size_t)row * CC;
  float s = p[lane] + p[lane + 64] + p[lane + 128] + p[lane + 192];
#pragma unroll
  for (int off = 32; off; off >>= 1) s += __shfl_xor(s, off);
  if (lane == 0) xm[row] = s * (1.0f / 256.0f);
}

// ---------------------------------------------------------------------------
// 2) amap[b,n] = sigmoid(conv3x3(xm_grid, mean_k(kernels)))  (zero pad)
__global__ void k_amap(const float* __restrict__ xm,
                       const float* __restrict__ kern,
                       float* __restrict__ amap) {
  int idx = blockIdx.x * 256 + threadIdx.x;  // 8192
  int b = idx >> 10, n = idx & 1023;
  int y = n >> 5, xq = n & 31;
  float km[9];
#pragma unroll
  for (int i = 0; i < 9; ++i)
    km[i] = 0.25f * (kern[i] + kern[9 + i] + kern[18 + i] + kern[27 + i]);
  float acc = 0.f;
#pragma unroll
  for (int dy = 0; dy < 3; ++dy) {
#pragma unroll
    for (int dx = 0; dx < 3; ++dx) {
      int yy = y + dy - 1, xx = xq + dx - 1;
      if (yy >= 0 && yy < 32 && xx >= 0 && xx < 32)
        acc += km[dy * 3 + dx] * xm[(b << 10) + (yy << 5) + xx];
    }
  }
  amap[idx] = 1.0f / (1.0f + __expf(-acc));
}

// ---------------------------------------------------------------------------
// 3) QKV GEMM: [8192x256] @ [768x256]^T + bias -> Q/K/V in [b,h,n,d]
__global__ __launch_bounds__(256) void k_qkv(
    const float* __restrict__ X, const float* __restrict__ W,
    const float* __restrict__ bias, float* __restrict__ Qb,
    float* __restrict__ Kb, float* __restrict__ Vb) {
  __shared__ float As[16][64];
  __shared__ float Bs[16][64];
  const int tid = threadIdx.x;
  const int bm = blockIdx.x << 6;
  const int bn = blockIdx.y << 6;
  const int tm = tid >> 4, tn = tid & 15;
  const int lrow = tid >> 2, lk = (tid & 3) << 2;
  const float* Arow = X + (size_t)(bm + lrow) * 256 + lk;
  const float* Brow = W + (size_t)(bn + lrow) * 256 + lk;
  float acc[4][4] = {};
  for (int k0 = 0; k0 < 256; k0 += 16) {
    float4 av = *(const float4*)(Arow + k0);
    float4 bv = *(const float4*)(Brow + k0);
    __syncthreads();
    As[lk + 0][lrow] = av.x; As[lk + 1][lrow] = av.y;
    As[lk + 2][lrow] = av.z; As[lk + 3][lrow] = av.w;
    Bs[lk + 0][lrow] = bv.x; Bs[lk + 1][lrow] = bv.y;
    Bs[lk + 2][lrow] = bv.z; Bs[lk + 3][lrow] = bv.w;
    __syncthreads();
#pragma unroll
    for (int k = 0; k < 16; ++k) {
      float4 a = *(const float4*)&As[k][tm << 2];
      float4 b4 = *(const float4*)&Bs[k][tn << 2];
      float avv[4] = {a.x, a.y, a.z, a.w};
      float bvv[4] = {b4.x, b4.y, b4.z, b4.w};
#pragma unroll
      for (int i = 0; i < 4; ++i)
#pragma unroll
        for (int j = 0; j < 4; ++j) acc[i][j] += avv[i] * bvv[j];
    }
  }
#pragma unroll
  for (int i = 0; i < 4; ++i) {
    int m = bm + (tm << 2) + i;
    int b = m >> 10, n = m & 1023;
#pragma unroll
    for (int j = 0; j < 4; ++j) {
      int c = bn + (tn << 2) + j;
      float v = acc[i][j] + bias[c];
      int which = c >> 8, h = (c >> 6) & 3, d = c & 63;
      float* dst = (which == 0) ? Qb : (which == 1) ? Kb : Vb;
      dst[((((size_t)b << 2) + h) << 16) + ((size_t)n << 6) + d] = v;
    }
  }
}

// ---------------------------------------------------------------------------
// 4) scores: P[bh,i,j] = 0.125*(q.k) + 0.1*amap[b,i]*amap[b,j]
__global__ __launch_bounds__(256) void k_scores(
    const float* __restrict__ Qb, const float* __restrict__ Kb,
    const float* __restrict__ amap, float* __restrict__ P) {
  __shared__ float As[16][64];
  __shared__ float Bs[16][64];
  const int tid = threadIdx.x;
  const int bh = blockIdx.z;
  const int b = bh >> 2;
  const float* A = Qb + ((size_t)bh << 16);
  const float* Bp = Kb + ((size_t)bh << 16);
  const int bm = blockIdx.x << 6, bn = blockIdx.y << 6;
  const int tm = tid >> 4, tn = tid & 15;
  const int lrow = tid >> 2, lk = (tid & 3) << 2;
  float acc[4][4] = {};
  for (int k0 = 0; k0 < 64; k0 += 16) {
    float4 av = *(const float4*)(A + (size_t)(bm + lrow) * 64 + k0 + lk);
    float4 bv = *(const float4*)(Bp + (size_t)(bn + lrow) * 64 + k0 + lk);
    __syncthreads();
    As[lk + 0][lrow] = av.x; As[lk + 1][lrow] = av.y;
    As[lk + 2][lrow] = av.z; As[lk + 3][lrow] = av.w;
    Bs[lk + 0][lrow] = bv.x; Bs[lk + 1][lrow] = bv.y;
    Bs[lk + 2][lrow] = bv.z; Bs[lk + 3][lrow] = bv.w;
    __syncthreads();
#pragma unroll
    for (int k = 0; k < 16; ++k) {
      float4 a = *(const float4*)&As[k][tm << 2];
      float4 b4 = *(const float4*)&Bs[k][tn << 2];
      float avv[4] = {a.x, a.y, a.z, a.w};
      float bvv[4] = {b4.x, b4.y, b4.z, b4.w};
#pragma unroll
      for (int i = 0; i < 4; ++i)
#pragma unroll
        for (int j = 0; j < 4; ++j) acc[i][j] += avv[i] * bvv[j];
    }
  }
  float amr[4], amc[4];
#pragma unroll
  for (int i = 0; i < 4; ++i) amr[i] = amap[(b << 10) + bm + (tm << 2) + i];
#pragma unroll
  for (int j = 0; j < 4; ++j) amc[j] = amap[(b << 10) + bn + (tn << 2) + j];
#pragma unroll
  for (int i = 0; i < 4; ++i) {
    size_t rowoff = ((size_t)bh << 20) + ((size_t)(bm + (tm << 2) + i) << 10);
#pragma unroll
    for (int j = 0; j < 4; ++j) {
      P[rowoff + bn + (tn << 2) + j] =
          acc[i][j] * 0.125f + 0.1f * amr[i] * amc[j];
    }
  }
}

// ---------------------------------------------------------------------------
// 5) softmax in-place over last dim of P (one wave per row)
__global__ void k_softmax(float* __restrict__ P) {
  int row = (blockIdx.x << 2) + (threadIdx.x >> 6);
  int lane = threadIdx.x & 63;
  float4* p = (float4*)(P + ((size_t)row << 10));
  float4 v[4];
  float mx = -3.4e38f;
#pragma unroll
  for (int c2 = 0; c2 < 4; ++c2) {
    v[c2] = p[(c2 << 6) + lane];
    mx = fmaxf(mx, fmaxf(fmaxf(v[c2].x, v[c2].y), fmaxf(v[c2].z, v[c2].w)));
  }
#pragma unroll
  for (int off = 32; off; off >>= 1) mx = fmaxf(mx, __shfl_xor(mx, off));
  float sum = 0.f;
#pragma unroll
  for (int c2 = 0; c2 < 4; ++c2) {
    v[c2].x = __expf(v[c2].x - mx); v[c2].y = __expf(v[c2].y - mx);
    v[c2].z = __expf(v[c2].z - mx); v[c2].w = __expf(v[c2].w - mx);
    sum += v[c2].x + v[c2].y + v[c2].z + v[c2].w;
  }
#pragma unroll
  for (int off = 32; off; off >>= 1) sum += __shfl_xor(sum, off);
  float inv = 1.0f / sum;
#pragma unroll
  for (int c2 = 0; c2 < 4; ++c2) {
    v[c2].x *= inv; v[c2].y *= inv; v[c2].z *= inv; v[c2].w *= inv;
    p[(c2 << 6) + lane] = v[c2];
  }
}

// ---------------------------------------------------------------------------
// 6) PV: OH[b,n,h*64+d] = sum_j P[bh,n,j] * V[bh,j,d]
__global__ __launch_bounds__(256) void k_pv(const float* __restrict__ P,
                                            const float* __restrict__ Vb,
                                            float* __restrict__ OH) {
  __shared__ float As[16][64];
  __shared__ float Bs[16][64];
  const int tid = threadIdx.x;
  const int bh = blockIdx.z;
  const int b = bh >> 2, h = bh & 3;
  const float* A = P + ((size_t)bh << 20);
  const float* V = Vb + ((size_t)bh << 16);
  const int bm = blockIdx.x << 6;
  const int tm = tid >> 4, tn = tid & 15;
  const int lrow = tid >> 2, lk = (tid & 3) << 2;
  const int kk = tid >> 4, dq = (tid & 15) << 2;
  float acc[4][4] = {};
  for (int j0 = 0; j0 < 1024; j0 += 16) {
    float4 av = *(const float4*)(A + ((size_t)(bm + lrow) << 10) + j0 + lk);
    float4 bv = *(const float4*)(V + (size_t)(j0 + kk) * 64 + dq);
    __syncthreads();
    As[lk + 0][lrow] = av.x; As[lk + 1][lrow] = av.y;
    As[lk + 2][lrow] = av.z; As[lk + 3][lrow] = av.w;
    *(float4*)&Bs[kk][dq] = bv;
    __syncthreads();
#pragma unroll
    for (int k = 0; k < 16; ++k) {
      float4 a = *(const float4*)&As[k][tm << 2];
      float4 b4 = *(const float4*)&Bs[k][tn << 2];
      float avv[4] = {a.x, a.y, a.z, a.w};
      float bvv[4] = {b4.x, b4.y, b4.z, b4.w};
#pragma unroll
      for (int i = 0; i < 4; ++i)
#pragma unroll
        for (int j = 0; j < 4; ++j) acc[i][j] += avv[i] * bvv[j];
    }
  }
#pragma unroll
  for (int i = 0; i < 4; ++i) {
    size_t rowoff = ((size_t)((b << 10) + bm + (tm << 2) + i) << 8) + (h << 6);
#pragma unroll
    for (int j = 0; j < 4; ++j) OH[rowoff + (tn << 2) + j] = acc[i][j];
  }
}

// ---------------------------------------------------------------------------
// 7) attention_weights = mean over heads (float4 elementwise)
__global__ void k_mean(const float* __restrict__ P, float* __restrict__ AW) {
  size_t idx = (size_t)blockIdx.x * 256 + threadIdx.x;  // 2,097,152 float4s
  size_t b = idx >> 18;          // 262144 float4s per b
  size_t off = idx & 262143;
  const float4* p = (const float4*)P;
  float4* aw = (float4*)AW;
  size_t base = (b << 20) + off;           // b*4*262144 float4s
  float4 a0 = p[base];
  float4 a1 = p[base + 262144];
  float4 a2 = p[base + 2 * 262144];
  float4 a3 = p[base + 3 * 262144];
  float4 r;
  r.x = 0.25f * (a0.x + a1.x + a2.x + a3.x);
  r.y = 0.25f * (a0.y + a1.y + a2.y + a3.y);
  r.z = 0.25f * (a0.z + a1.z + a2.z + a3.z);
  r.w = 0.25f * (a0.w + a1.w + a2.w + a3.w);
  aw[(b << 18) + off] = r;
}

// ---------------------------------------------------------------------------
// 8) proj GEMM: out = OH @ proj_w^T + proj_b
__global__ __launch_bounds__(256) void k_proj(const float* __restrict__ X,
                                              const float* __restrict__ W,
                                              const float* __restrict__ bias,
                                              float* __restrict__ out) {
  __shared__ float As[16][64];
  __shared__ float Bs[16][64];
  const int tid = threadIdx.x;
  const int bm = blockIdx.x << 6;
  const int bn = blockIdx.y << 6;
  const int tm = tid >> 4, tn = tid & 15;
  const int lrow = tid >> 2, lk = (tid & 3) << 2;
  const float* Arow = X + (size_t)(bm + lrow) * 256 + lk;
  const float* Brow = W + (size_t)(bn + lrow) * 256 + lk;
  float acc[4][4] = {};
  for (int k0 = 0; k0 < 256; k0 += 16) {
    float4 av = *(const float4*)(Arow + k0);
    float4 bv = *(const float4*)(Brow + k0);
    __syncthreads();
    As[lk + 0][lrow] = av.x; As[lk + 1][lrow] = av.y;
    As[lk + 2][lrow] = av.z; As[lk + 3][lrow] = av.w;
    Bs[lk + 0][lrow] = bv.x; Bs[lk + 1][lrow] = bv.y;
    Bs[lk + 2][lrow] = bv.z; Bs[lk + 3][lrow] = bv.w;
    __syncthreads();
#pragma unroll
    for (int k = 0; k < 16; ++k) {
      float4 a = *(const float4*)&As[k][tm << 2];
      float4 b4 = *(const float4*)&Bs[k][tn << 2];
      float avv[4] = {a.x, a.y, a.z, a.w};
      float bvv[4] = {b4.x, b4.y, b4.z, b4.w};
#pragma unroll
      for (int i = 0; i < 4; ++i)
#pragma unroll
        for (int j = 0; j < 4; ++j) acc[i][j] += avv[i] * bvv[j];
    }
  }
#pragma unroll
  for (int i = 0; i < 4; ++i) {
    int m = bm + (tm << 2) + i;
#pragma unroll
    for (int j = 0; j < 4; ++j) {
      int c = bn + (tn << 2) + j;
      out[((size_t)m << 8) + c] = acc[i][j] + bias[c];
    }
  }
}

// ---------------------------------------------------------------------------
// 9) reg loss = sum_k mean((k - C)^2) + 0.01*sum|k|
__global__ void k_reg(const float* __restrict__ kern, float* __restrict__ out) {
  const float Cst[36] = {
      // ARC
      -1.f, -1.f, -1.f, 2.f, 2.f, 2.f, -1.f, -1.f, -1.f,
      // CURV3 (5x5 -> 3x3 separable bilinear, align_corners=False)
      -0.11111111f, 0.f, -0.11111111f, 0.f, 4.f, 0.f,
      -0.11111111f, 0.f, -0.11111111f,
      // RAD
      0.f, -1.f, 0.f, -1.f, 4.f, -1.f, 0.f, -1.f, 0.f,
      // TAN
      -1.f, 0.f, -1.f, 0.f, 4.f, 0.f, -1.f, 0.f, -1.f};
  int t = threadIdx.x;
  float v = 0.f;
  if (t < 36) {
    float kv = kern[t];
    float d = kv - Cst[t];
    v = d * d * (1.0f / 9.0f) + 0.01f * fabsf(kv);
  }
#pragma unroll
  for (int off = 32; off; off >>= 1) v += __shfl_xor(v, off);
  if (t == 0) out[0] = v;
}

// ---------------------------------------------------------------------------
extern "C" void kernel_launch(void* const* d_in, const int* in_sizes, int n_in,
                              void* d_out, int out_size, void* d_ws,
                              size_t ws_size, hipStream_t stream) {
  const float* x = (const float*)d_in[0];
  const float* qkv_w = (const float*)d_in[1];
  const float* qkv_b = (const float*)d_in[2];
  const float* proj_w = (const float*)d_in[3];
  const float* proj_b = (const float*)d_in[4];
  const float* kern = (const float*)d_in[5];

  float* out = (float*)d_out;            // [8,1024,256]
  float* aw = out + 2097152;             // [8,1024,1024]
  float* rl = out + 10485760;            // scalar

  float* ws = (float*)d_ws;
  float* xm = ws;                        // 8192
  float* amap = ws + 8192;               // 8192
  float* Qb = ws + 16384;                // 2,097,152
  float* Kb = Qb + 2097152;
  float* Vb = Kb + 2097152;
  float* OH = Vb + 2097152;              // 2,097,152
  float* P = OH + 2097152;               // 33,554,432

  k_xm<<<2048, 256, 0, stream>>>(x, xm);
  k_amap<<<32, 256, 0, stream>>>(xm, kern, amap);
  k_qkv<<<dim3(128, 12), 256, 0, stream>>>(x, qkv_w, qkv_b, Qb, Kb, Vb);
  k_scores<<<dim3(16, 16, 32), 256, 0, stream>>>(Qb, Kb, amap, P);
  k_softmax<<<8192, 256, 0, stream>>>(P);
  k_pv<<<dim3(16, 1, 32), 256, 0, stream>>>(P, Vb, OH);
  k_mean<<<8192, 256, 0, stream>>>(P, aw);
  k_proj<<<dim3(128, 4), 256, 0, stream>>>(OH, proj_w, proj_b, out);
  k_reg<<<1, 64, 0, stream>>>(kern, rl);
}

// Round 2
// 215.202 us; speedup vs baseline: 1.6447x; 1.6447x over previous
//
#include <hip/hip_runtime.h>
#include <cstdint>

// Problem constants: B=8, N=1024, C=256, heads=4, hd=64
typedef _Float16 h16;
typedef __attribute__((ext_vector_type(8))) _Float16 f16x8;
typedef __attribute__((ext_vector_type(4))) _Float16 f16x4;
typedef __attribute__((ext_vector_type(4))) float f32x4;

// ---------------------------------------------------------------------------
// 1) xm[b,n] = mean over C of x[b,n,:]   (one wave per row)
__global__ void k_xm(const float* __restrict__ x, float* __restrict__ xm) {
  int row = (blockIdx.x << 2) + (threadIdx.x >> 6);
  int lane = threadIdx.x & 63;
  const float* p = x + (size_t)row * 256;
  float s = p[lane] + p[lane + 64] + p[lane + 128] + p[lane + 192];
#pragma unroll
  for (int off = 32; off; off >>= 1) s += __shfl_xor(s, off);
  if (lane == 0) xm[row] = s * (1.0f / 256.0f);
}

// ---------------------------------------------------------------------------
// 2) amap[b,n] = sigmoid(conv3x3(xm_grid, mean_k(kernels)))  (zero pad)
__global__ void k_amap(const float* __restrict__ xm,
                       const float* __restrict__ kern,
                       float* __restrict__ amap) {
  int idx = blockIdx.x * 256 + threadIdx.x;  // 8192
  int b = idx >> 10, n = idx & 1023;
  int y = n >> 5, xq = n & 31;
  float km[9];
#pragma unroll
  for (int i = 0; i < 9; ++i)
    km[i] = 0.25f * (kern[i] + kern[9 + i] + kern[18 + i] + kern[27 + i]);
  float acc = 0.f;
#pragma unroll
  for (int dy = 0; dy < 3; ++dy) {
#pragma unroll
    for (int dx = 0; dx < 3; ++dx) {
      int yy = y + dy - 1, xx = xq + dx - 1;
      if (yy >= 0 && yy < 32 && xx >= 0 && xx < 32)
        acc += km[dy * 3 + dx] * xm[(b << 10) + (yy << 5) + xx];
    }
  }
  amap[idx] = 1.0f / (1.0f + __expf(-acc));
}

// ---------------------------------------------------------------------------
// 3) cast x, qkv_w, proj_w to fp16 (4 elems/thread)
__global__ void k_cast(const float* __restrict__ x, const float* __restrict__ qw,
                       const float* __restrict__ pw, h16* __restrict__ xh,
                       h16* __restrict__ qwh, h16* __restrict__ pwh) {
  int i4 = blockIdx.x * 256 + threadIdx.x;  // 589824 total
  const float* src;
  h16* dst;
  int off;
  if (i4 < 524288) { src = x; dst = xh; off = i4; }
  else if (i4 < 573440) { src = qw; dst = qwh; off = i4 - 524288; }
  else { src = pw; dst = pwh; off = i4 - 573440; }
  float4 v = ((const float4*)src)[off];
  f16x4 o = {(h16)v.x, (h16)v.y, (h16)v.z, (h16)v.w};
  ((f16x4*)dst)[off] = o;
}

// ---------------------------------------------------------------------------
// 4) QKV GEMM via MFMA: [8192x256]fp16 @ [768x256]^T fp16 + bias(fp32)
//    writes Qh,Kh as [b,h,n,64] fp16, V transposed Vt as [b,h,64,1024] fp16
__global__ __launch_bounds__(128) void k_qkv(
    const h16* __restrict__ xh, const h16* __restrict__ qwh,
    const float* __restrict__ bias, h16* __restrict__ Qh,
    h16* __restrict__ Kh, h16* __restrict__ Vt) {
  const int w = threadIdx.x >> 6, lane = threadIdx.x & 63;
  const int g = lane >> 4, li = lane & 15;
  const int tile = blockIdx.x * 2 + w;  // 0..3071
  const int tr = tile & 255, tc = tile >> 8;
  const int r0 = tr * 32, c0 = tc * 64;
  f32x4 acc[2][4];
#pragma unroll
  for (int mr = 0; mr < 2; ++mr)
#pragma unroll
    for (int nc = 0; nc < 4; ++nc) acc[mr][nc] = {0.f, 0.f, 0.f, 0.f};
  for (int ks = 0; ks < 8; ++ks) {
    int k0 = ks * 32 + g * 8;
    f16x8 a[2], bf[4];
#pragma unroll
    for (int mr = 0; mr < 2; ++mr)
      a[mr] = *(const f16x8*)(xh + (size_t)(r0 + mr * 16 + li) * 256 + k0);
#pragma unroll
    for (int nc = 0; nc < 4; ++nc)
      bf[nc] = *(const f16x8*)(qwh + (size_t)(c0 + nc * 16 + li) * 256 + k0);
#pragma unroll
    for (int mr = 0; mr < 2; ++mr)
#pragma unroll
      for (int nc = 0; nc < 4; ++nc)
        acc[mr][nc] = __builtin_amdgcn_mfma_f32_16x16x32_f16(a[mr], bf[nc],
                                                             acc[mr][nc], 0, 0, 0);
  }
  const int which = c0 >> 8;       // 0=Q 1=K 2=V
  const int hh = (c0 >> 6) & 3;    // head
#pragma unroll
  for (int nc = 0; nc < 4; ++nc) {
    int d = nc * 16 + li;          // 0..63 within head
    float bv = bias[c0 + d];
#pragma unroll
    for (int mr = 0; mr < 2; ++mr) {
#pragma unroll
      for (int r = 0; r < 4; ++r) {
        int m = r0 + mr * 16 + g * 4 + r;
        int bq = m >> 10, n = m & 1023;
        float v = acc[mr][nc][r] + bv;
        size_t base = ((size_t)(bq * 4 + hh)) << 16;
        if (which == 0) Qh[base + (size_t)n * 64 + d] = (h16)v;
        else if (which == 1) Kh[base + (size_t)n * 64 + d] = (h16)v;
        else Vt[base + (size_t)d * 1024 + n] = (h16)v;
      }
    }
  }
}

// ---------------------------------------------------------------------------
// 5) fused attention: scores+prior -> softmax (2-pass flash) -> PV + AW mean
//    block = (b, 32-row tile); 4 waves, wave = head. P staged in swizzled LDS.
__device__ __forceinline__ void compute_S(const h16* __restrict__ Kp,
                                          const float* __restrict__ am, int j0,
                                          const f16x8 (&qf)[2][2],
                                          const float (&am_r)[2][4], int g,
                                          int li, f32x4 (&s)[2][4]) {
  f16x8 kf[4][2];
#pragma unroll
  for (int nc = 0; nc < 4; ++nc)
#pragma unroll
    for (int ks = 0; ks < 2; ++ks)
      kf[nc][ks] =
          *(const f16x8*)(Kp + (size_t)(j0 + nc * 16 + li) * 64 + ks * 32 + g * 8);
#pragma unroll
  for (int mr = 0; mr < 2; ++mr)
#pragma unroll
    for (int nc = 0; nc < 4; ++nc) {
      f32x4 a = {0.f, 0.f, 0.f, 0.f};
      a = __builtin_amdgcn_mfma_f32_16x16x32_f16(qf[mr][0], kf[nc][0], a, 0, 0, 0);
      a = __builtin_amdgcn_mfma_f32_16x16x32_f16(qf[mr][1], kf[nc][1], a, 0, 0, 0);
      s[mr][nc] = a;
    }
#pragma unroll
  for (int mr = 0; mr < 2; ++mr)
#pragma unroll
    for (int nc = 0; nc < 4; ++nc) {
      float amc = am[j0 + nc * 16 + li];
#pragma unroll
      for (int r = 0; r < 4; ++r)
        s[mr][nc][r] = s[mr][nc][r] * 0.125f + am_r[mr][r] * amc;
    }
}

__global__ __launch_bounds__(256) void k_attn(
    const h16* __restrict__ Qh, const h16* __restrict__ Kh,
    const h16* __restrict__ Vt, const float* __restrict__ amap,
    h16* __restrict__ OHh, float* __restrict__ AW) {
  __shared__ __align__(16) unsigned char Pst[4][4096];  // per-head 32x64 h16, swizzled
  const int tid = threadIdx.x;
  const int h = tid >> 6, lane = tid & 63, g = lane >> 4, li = lane & 15;
  const int b = blockIdx.x & 7, rt = blockIdx.x >> 3;
  const int r0 = rt * 32;
  const size_t base = ((size_t)(b * 4 + h)) << 16;
  const h16* Kp = Kh + base;
  const float* am = amap + (b << 10);

  f16x8 qf[2][2];
#pragma unroll
  for (int mr = 0; mr < 2; ++mr)
#pragma unroll
    for (int ks = 0; ks < 2; ++ks)
      qf[mr][ks] =
          *(const f16x8*)(Qh + base + (size_t)(r0 + mr * 16 + li) * 64 + ks * 32 + g * 8);

  float am_r[2][4];  // 0.1 * amap[row] (prior weight folded in)
#pragma unroll
  for (int mr = 0; mr < 2; ++mr)
#pragma unroll
    for (int r = 0; r < 4; ++r)
      am_r[mr][r] = 0.1f * am[r0 + mr * 16 + g * 4 + r];

  float m_run[2][4], l_run[2][4];
#pragma unroll
  for (int mr = 0; mr < 2; ++mr)
#pragma unroll
    for (int r = 0; r < 4; ++r) { m_run[mr][r] = -1e30f; l_run[mr][r] = 0.f; }

  // ---- pass A: row stats (online max / expsum) ----
  for (int jt = 0; jt < 16; ++jt) {
    f32x4 s[2][4];
    compute_S(Kp, am, jt * 64, qf, am_r, g, li, s);
#pragma unroll
    for (int mr = 0; mr < 2; ++mr) {
#pragma unroll
      for (int r = 0; r < 4; ++r) {
        float mx = fmaxf(fmaxf(s[mr][0][r], s[mr][1][r]),
                         fmaxf(s[mr][2][r], s[mr][3][r]));
        mx = fmaxf(mx, __shfl_xor(mx, 1));
        mx = fmaxf(mx, __shfl_xor(mx, 2));
        mx = fmaxf(mx, __shfl_xor(mx, 4));
        mx = fmaxf(mx, __shfl_xor(mx, 8));
        float mnew = fmaxf(m_run[mr][r], mx);
        float ps = __expf(s[mr][0][r] - mnew) + __expf(s[mr][1][r] - mnew) +
                   __expf(s[mr][2][r] - mnew) + __expf(s[mr][3][r] - mnew);
        ps += __shfl_xor(ps, 1);
        ps += __shfl_xor(ps, 2);
        ps += __shfl_xor(ps, 4);
        ps += __shfl_xor(ps, 8);
        l_run[mr][r] = l_run[mr][r] * __expf(m_run[mr][r] - mnew) + ps;
        m_run[mr][r] = mnew;
      }
    }
  }
  float rinv[2][4];
#pragma unroll
  for (int mr = 0; mr < 2; ++mr)
#pragma unroll
    for (int r = 0; r < 4; ++r) rinv[mr][r] = 1.0f / l_run[mr][r];

  // ---- pass B: normalized P -> LDS; PV MFMA; AW tile write ----
  f32x4 o[2][4];
#pragma unroll
  for (int mr = 0; mr < 2; ++mr)
#pragma unroll
    for (int nd = 0; nd < 4; ++nd) o[mr][nd] = {0.f, 0.f, 0.f, 0.f};

  for (int jt = 0; jt < 16; ++jt) {
    const int j0 = jt * 64;
    f32x4 s[2][4];
    compute_S(Kp, am, j0, qf, am_r, g, li, s);
    __syncthreads();  // previous iter's readers done before overwrite
#pragma unroll
    for (int mr = 0; mr < 2; ++mr) {
#pragma unroll
      for (int nc = 0; nc < 4; ++nc) {
        int colb = (nc * 16 + li) * 2;
#pragma unroll
        for (int r = 0; r < 4; ++r) {
          int row = mr * 16 + g * 4 + r;
          float p = __expf(s[mr][nc][r] - m_run[mr][r]) * rinv[mr][r];
          *(h16*)(&Pst[h][(row << 7) + (colb ^ ((row & 7) << 4))]) = (h16)p;
        }
      }
    }
    __syncthreads();
    // PV: O += P @ V  (A from swizzled LDS, B from pre-transposed Vt)
    f16x8 vf[4][2], af[2][2];
#pragma unroll
    for (int nd = 0; nd < 4; ++nd)
#pragma unroll
      for (int ks = 0; ks < 2; ++ks)
        vf[nd][ks] = *(const f16x8*)(Vt + base + (size_t)(nd * 16 + li) * 1024 +
                                     j0 + ks * 32 + g * 8);
#pragma unroll
    for (int mr = 0; mr < 2; ++mr)
#pragma unroll
      for (int ks = 0; ks < 2; ++ks) {
        int row = mr * 16 + li;
        int colb = (ks * 32 + g * 8) * 2;
        af[mr][ks] =
            *(const f16x8*)(&Pst[h][(row << 7) + (colb ^ ((row & 7) << 4))]);
      }
#pragma unroll
    for (int mr = 0; mr < 2; ++mr)
#pragma unroll
      for (int nd = 0; nd < 4; ++nd) {
        o[mr][nd] = __builtin_amdgcn_mfma_f32_16x16x32_f16(af[mr][0], vf[nd][0],
                                                           o[mr][nd], 0, 0, 0);
        o[mr][nd] = __builtin_amdgcn_mfma_f32_16x16x32_f16(af[mr][1], vf[nd][1],
                                                           o[mr][nd], 0, 0, 0);
      }
    // AW tile: all 256 threads sum the 4 head quadrants
    {
      int row = tid >> 3, c8 = (tid & 7) * 8;
      float sum[8] = {0.f, 0.f, 0.f, 0.f, 0.f, 0.f, 0.f, 0.f};
#pragma unroll
      for (int hh = 0; hh < 4; ++hh) {
        f16x8 q = *(const f16x8*)(&Pst[hh][(row << 7) +
                                           ((c8 * 2) ^ ((row & 7) << 4))]);
#pragma unroll
        for (int i = 0; i < 8; ++i) sum[i] += (float)q[i];
      }
      float* dst = AW + ((size_t)b << 20) + (size_t)(r0 + row) * 1024 + j0 + c8;
      float4 o1 = {0.25f * sum[0], 0.25f * sum[1], 0.25f * sum[2], 0.25f * sum[3]};
      float4 o2 = {0.25f * sum[4], 0.25f * sum[5], 0.25f * sum[6], 0.25f * sum[7]};
      *(float4*)dst = o1;
      *(float4*)(dst + 4) = o2;
    }
  }
  // epilogue: write per-head output rows as fp16 [b,n,256]
#pragma unroll
  for (int mr = 0; mr < 2; ++mr)
#pragma unroll
    for (int nd = 0; nd < 4; ++nd)
#pragma unroll
      for (int r = 0; r < 4; ++r)
        OHh[(size_t)((b << 10) + r0 + mr * 16 + g * 4 + r) * 256 + h * 64 +
            nd * 16 + li] = (h16)o[mr][nd][r];
}

// ---------------------------------------------------------------------------
// 6) proj GEMM via MFMA: out = OHh @ proj_w^T + proj_b  (fp32 out)
__global__ __launch_bounds__(128) void k_proj(const h16* __restrict__ OHh,
                                              const h16* __restrict__ pwh,
                                              const float* __restrict__ bias,
                                              float* __restrict__ out) {
  const int w = threadIdx.x >> 6, lane = threadIdx.x & 63;
  const int g = lane >> 4, li = lane & 15;
  const int tile = blockIdx.x * 2 + w;  // 0..1023
  const int tc = tile & 3, tr = tile >> 2;
  const int r0 = tr * 32, c0 = tc * 64;
  f32x4 acc[2][4];
#pragma unroll
  for (int mr = 0; mr < 2; ++mr)
#pragma unroll
    for (int nc = 0; nc < 4; ++nc) acc[mr][nc] = {0.f, 0.f, 0.f, 0.f};
  for (int ks = 0; ks < 8; ++ks) {
    int k0 = ks * 32 + g * 8;
    f16x8 a[2], bf[4];
#pragma unroll
    for (int mr = 0; mr < 2; ++mr)
      a[mr] = *(const f16x8*)(OHh + (size_t)(r0 + mr * 16 + li) * 256 + k0);
#pragma unroll
    for (int nc = 0; nc < 4; ++nc)
      bf[nc] = *(const f16x8*)(pwh + (size_t)(c0 + nc * 16 + li) * 256 + k0);
#pragma unroll
    for (int mr = 0; mr < 2; ++mr)
#pragma unroll
      for (int nc = 0; nc < 4; ++nc)
        acc[mr][nc] = __builtin_amdgcn_mfma_f32_16x16x32_f16(a[mr], bf[nc],
                                                             acc[mr][nc], 0, 0, 0);
  }
#pragma unroll
  for (int nc = 0; nc < 4; ++nc) {
    int c = c0 + nc * 16 + li;
    float bv = bias[c];
#pragma unroll
    for (int mr = 0; mr < 2; ++mr)
#pragma unroll
      for (int r = 0; r < 4; ++r) {
        int m = r0 + mr * 16 + g * 4 + r;
        out[(size_t)m * 256 + c] = acc[mr][nc][r] + bv;
      }
  }
}

// ---------------------------------------------------------------------------
// 7) reg loss = sum_k mean((k - C)^2) + 0.01*sum|k|
__global__ void k_reg(const float* __restrict__ kern, float* __restrict__ out) {
  const float Cst[36] = {
      -1.f, -1.f, -1.f, 2.f, 2.f, 2.f, -1.f, -1.f, -1.f,
      -0.11111111f, 0.f, -0.11111111f, 0.f, 4.f, 0.f,
      -0.11111111f, 0.f, -0.11111111f,
      0.f, -1.f, 0.f, -1.f, 4.f, -1.f, 0.f, -1.f, 0.f,
      -1.f, 0.f, -1.f, 0.f, 4.f, 0.f, -1.f, 0.f, -1.f};
  int t = threadIdx.x;
  float v = 0.f;
  if (t < 36) {
    float kv = kern[t];
    float d = kv - Cst[t];
    v = d * d * (1.0f / 9.0f) + 0.01f * fabsf(kv);
  }
#pragma unroll
  for (int off = 32; off; off >>= 1) v += __shfl_xor(v, off);
  if (t == 0) out[0] = v;
}

// ---------------------------------------------------------------------------
extern "C" void kernel_launch(void* const* d_in, const int* in_sizes, int n_in,
                              void* d_out, int out_size, void* d_ws,
                              size_t ws_size, hipStream_t stream) {
  const float* x = (const float*)d_in[0];
  const float* qkv_w = (const float*)d_in[1];
  const float* qkv_b = (const float*)d_in[2];
  const float* proj_w = (const float*)d_in[3];
  const float* proj_b = (const float*)d_in[4];
  const float* kern = (const float*)d_in[5];

  float* out = (float*)d_out;   // [8,1024,256]
  float* aw = out + 2097152;    // [8,1024,1024]
  float* rl = out + 10485760;   // scalar

  float* xm = (float*)d_ws;     // 8192 f32
  float* amap = xm + 8192;      // 8192 f32
  h16* xh = (h16*)(amap + 8192);  // 2097152
  h16* qwh = xh + 2097152;        // 196608
  h16* pwh = qwh + 196608;        // 65536
  h16* Qh = pwh + 65536;          // 2097152  [b,h,n,64]
  h16* Kh = Qh + 2097152;         // 2097152  [b,h,n,64]
  h16* Vt = Kh + 2097152;         // 2097152  [b,h,64,1024]
  h16* OHh = Vt + 2097152;        // 2097152  [b,n,256]

  k_xm<<<2048, 256, 0, stream>>>(x, xm);
  k_amap<<<32, 256, 0, stream>>>(xm, kern, amap);
  k_cast<<<2304, 256, 0, stream>>>(x, qkv_w, proj_w, xh, qwh, pwh);
  k_qkv<<<1536, 128, 0, stream>>>(xh, qwh, qkv_b, Qh, Kh, Vt);
  k_attn<<<256, 256, 0, stream>>>(Qh, Kh, Vt, amap, OHh, aw);
  k_proj<<<512, 128, 0, stream>>>(OHh, pwh, proj_b, out);
  k_reg<<<1, 64, 0, stream>>>(kern, rl);
}